// Round 11
// baseline (312.791 us; speedup 1.0000x reference)
//
#include <hip/hip_runtime.h>

using f32x4  = __attribute__((ext_vector_type(4))) float;
using bf16x8 = __attribute__((ext_vector_type(8))) __bf16;
using u16x4  = __attribute__((ext_vector_type(4))) unsigned short;

#define BK 64
#define REG_HALF   8192      // ushorts: 128 rows x 64 cols
#define A_OFS      0
#define B_OFS      16384
#define BUF_STRIDE 32768     // one buffer = A(32KB)+B(32KB) = 64 KB

#define BARRIER() __builtin_amdgcn_s_barrier()
#define SGB()     __builtin_amdgcn_sched_barrier(0)

__device__ __forceinline__ unsigned short f32_to_bf16_bits(float f) {
    unsigned int u = __builtin_bit_cast(unsigned int, f);
    u = (u + 0x7fffu + ((u >> 16) & 1u)) >> 16;
    return (unsigned short)u;
}

__device__ __forceinline__ void gload_lds16(const void* g, void* l) {
    __builtin_amdgcn_global_load_lds(
        (const __attribute__((address_space(1))) unsigned int*)g,
        (__attribute__((address_space(3))) unsigned int*)l,
        16, 0, 0);
}

// ---------------------------------------------------------------------------
// Fused prep: fake-quant x (exact-f32 math, bf16 store) + W f32->bf16.
// t4x % 256 == 0 so no wave straddles the boundary (16-lane shfl groups OK).
// ---------------------------------------------------------------------------
__global__ void prep_kernel(const float* __restrict__ x,
                            const float* __restrict__ W,
                            unsigned short* __restrict__ xq,
                            unsigned short* __restrict__ Wb,
                            int t4x, int t4w) {
    int idx = blockIdx.x * 256 + threadIdx.x;
    if (idx < t4x) {
        f32x4 v = *(const f32x4*)(x + (size_t)idx * 4);
        float am = fmaxf(fmaxf(fabsf(v[0]), fabsf(v[1])),
                         fmaxf(fabsf(v[2]), fabsf(v[3])));
        am = fmaxf(am, __shfl_xor(am, 1));
        am = fmaxf(am, __shfl_xor(am, 2));
        am = fmaxf(am, __shfl_xor(am, 4));
        am = fmaxf(am, __shfl_xor(am, 8));
        float delta = fmaxf(am / 127.0f, 1e-5f);
        u16x4 o;
#pragma unroll
        for (int i = 0; i < 4; ++i) {
            float q = rintf(v[i] / delta);           // round-half-even
            q = fminf(fmaxf(q, -127.0f), 127.0f);
            o[i] = f32_to_bf16_bits(q * delta);
        }
        *(u16x4*)(xq + (size_t)idx * 4) = o;
    } else {
        int j = idx - t4x;
        if (j < t4w) {
            f32x4 v = *(const f32x4*)(W + (size_t)j * 4);
            u16x4 o;
#pragma unroll
            for (int i = 0; i < 4; ++i) o[i] = f32_to_bf16_bits(v[i]);
            *(u16x4*)(Wb + (size_t)j * 4) = o;
        }
    }
}

// Fragment readers (region base pointer; T2-swizzled column) ---------------
__device__ __forceinline__ void read_af(bf16x8 (&dst)[4][2],
    const unsigned short* reg, int wm, int lr, int lk, int sx) {
#pragma unroll
    for (int m = 0; m < 4; ++m)
#pragma unroll
        for (int kk = 0; kk < 2; ++kk)
            dst[m][kk] = *(const bf16x8*)(reg
                + (wm * 64 + m * 16 + lr) * 64 + ((((kk << 2) + lk) ^ sx) << 3));
}

__device__ __forceinline__ void read_bf(bf16x8 (&dst)[2][2],
    const unsigned short* reg, int wn, int lr, int lk, int sx) {
#pragma unroll
    for (int n = 0; n < 2; ++n)
#pragma unroll
        for (int kk = 0; kk < 2; ++kk)
            dst[n][kk] = *(const bf16x8*)(reg
                + (wn * 32 + n * 16 + lr) * 64 + ((((kk << 2) + lk) ^ sx) << 3));
}

__device__ __forceinline__ void mfma_quad(f32x4 (&acc)[8][4], int mo, int no,
    const bf16x8 (&af)[4][2], const bf16x8 (&bf)[2][2]) {
#pragma unroll
    for (int m = 0; m < 4; ++m)
#pragma unroll
        for (int n = 0; n < 2; ++n)
#pragma unroll
            for (int kk = 0; kk < 2; ++kk)
                acc[mo + m][no + n] = __builtin_amdgcn_mfma_f32_16x16x32_bf16(
                    af[m][kk], bf[n][kk], acc[mo + m][no + n], 0, 0, 0);
}

// ---------------------------------------------------------------------------
// 256x256 bf16 GEMM (B^T), rotated-window schedule:
// window p: { BARRIER ; setprio1 ; MFMA_p ; reads_{p+1} ; stage_p ;
//             setprio0 ; [vmcnt] ; SGB }
// Reads for phase p+1 issue in the MFMA_p shadow (no fence between M and
// reads); delivery absorbed by B(p+1) rendezvous + lgkm wait before M_{p+1}.
// Stage stream: P1: A-h1(t+1)->nb, P2: A-h0(t+2)->cb, P3: B-h1(t+2)->cb,
//               P4: B-h0(t+2)->cb.
// Reads: P1 issues bfB(t)<-cb.B-h1; P2 issues afH(t)<-cb.A-h1; P4 issues
//   afL(t+1)<-nb.A-h0 and bfA(t+1)<-nb.B-h0 (guarded t+1<NT).
// Single bfA/afL/afH/bfB sets (no e/o rotation): bfA(t) read (t-1).P4,
//   used Q1(t.P1) and Q3(t.P3); its region B-h0(t) not overwritten until
//   t.P4 -> no rotation pair needed (-8 VGPR vs round 10).
// vmcnt: end-P2 vmcnt(4), end-P4 vmcnt(4). Ledger (2 loads/call, induction
//   verified): end-P2 outstanding {(t-1)P3,(t-1)P4,tP1,tP2}=8 -> proves
//   through (t-1).P4; end-P4 outstanding {tP1..tP4}=8 -> proves through tP2.
// RAW (read issued after B(w); region proven by a wait before B(w)):
//   bfA/afL(t) staged (t-2).P4/(t-2).P2: proven end-(t-1).P2; read (t-1).P4.
//   bfB(t) staged (t-2).P3: proven end-(t-1).P2; read t.P1.
//   afH(t) staged (t-1).P1: proven end-(t-1).P4; read t.P2.
// WAR (stage after a barrier preceded by the dying region's consuming MFMA,
//   whose lgkm wait forced read delivery):
//   P1 nb.A-h1: read (t-2).P2, delivered < M((t-2).P3) < B(t.P1).
//   P2 cb.A-h0: afL(t) read (t-1).P4, delivered < M(t.P1) < B(t.P2).
//   P3 cb.B-h1: bfB(t) read t.P1, delivered < M(t.P2) < B(t.P3).
//   P4 cb.B-h0: bfA(t) read (t-1).P4, delivered < M(t.P1) < B(t.P4).
// Prologue c1..c7 (A-h0(0),B-h0(0),B-h1(0),A-h1(0),A-h0(1),B-h0(1),B-h1(1));
//   vmcnt(6) proves c1..c4; first-iter proofs check out (c5/c6 by 0.P2's
//   wait, c7 by it too, A-h1(1) staged 0.P1 by 0.P4's wait) = steady state.
// Tail: stage sources clamped to NT-1 (dead-region writes); P4 reads
//   guarded; vmcnt(0) drain after loop.
// ---------------------------------------------------------------------------
__global__ __launch_bounds__(512, 2) void gemm_kernel(
    const unsigned short* __restrict__ A,   // [M][K] bf16 bits (quantized x)
    const unsigned short* __restrict__ B,   // [N][K] bf16 bits (W)
    const float* __restrict__ bias,         // [N]
    float* __restrict__ out,                // [M][N] f32
    int M, int N, int K)
{
    __shared__ unsigned short lds[2 * BUF_STRIDE];   // 128 KiB

    const int tid  = threadIdx.x;
    const int lane = tid & 63;
    const int wv   = tid >> 6;
    const int wm   = wv >> 2;        // 0..1  (128 rows each)
    const int wn   = wv & 3;         // 0..3  (64 cols each)
    const int lr   = lane & 15;
    const int lk   = lane >> 4;      // 0..3
    const int sx   = lr & 7;

    const int nbn = N / 256;
    const int nwg = gridDim.x;
    const int cpx = nwg >> 3;        // bijective XCD swizzle (nwg % 8 == 0)
    const int swz = (blockIdx.x & 7) * cpx + (blockIdx.x >> 3);
    const int bm0 = (swz / nbn) * 256;
    const int bn0 = (swz % nbn) * 256;

    const unsigned short* Ag = A + (size_t)bm0 * K;
    const unsigned short* Bg = B + (size_t)bn0 * K;
    const int NT = K / BK;           // 64, even

    // Hoisted per-lane staging offsets (element units, 32-bit safe).
    const int gr0 = tid >> 3,         gr1 = (512 + tid) >> 3;
    const int c0  = ((tid & 7) ^ (gr0 & 7)) << 3;
    const int c1  = ((tid & 7) ^ (gr1 & 7)) << 3;
    const int offA0 = ((((gr0 >> 6) << 7) + (gr0 & 63))) * K + c0;
    const int offA1 = ((((gr1 >> 6) << 7) + (gr1 & 63))) * K + c1;
    const int offB0 = ((((gr0 >> 5) << 6) + (gr0 & 31))) * K + c0;
    const int offB1 = ((((gr1 >> 5) << 6) + (gr1 & 31))) * K + c1;
    const int ldsu0 = tid * 8, ldsu1 = (512 + tid) * 8;

#define STAGE_AH0(TK, DST) { gload_lds16(Ag + offA0 + (TK), (DST) + ldsu0); \
                             gload_lds16(Ag + offA1 + (TK), (DST) + ldsu1); }
#define STAGE_AH1(TK, DST) { gload_lds16(Ag + offA0 + 64*K + (TK), (DST) + ldsu0); \
                             gload_lds16(Ag + offA1 + 64*K + (TK), (DST) + ldsu1); }
#define STAGE_BH0(TK, DST) { gload_lds16(Bg + offB0 + (TK), (DST) + ldsu0); \
                             gload_lds16(Bg + offB1 + (TK), (DST) + ldsu1); }
#define STAGE_BH1(TK, DST) { gload_lds16(Bg + offB0 + 32*K + (TK), (DST) + ldsu0); \
                             gload_lds16(Bg + offB1 + 32*K + (TK), (DST) + ldsu1); }

    f32x4 acc[8][4] = {};

    // Prologue, ledger order c1..c7 (oldest first):
    STAGE_AH0(0,  lds + A_OFS);                          // c1 A-h0(0)
    STAGE_BH0(0,  lds + B_OFS);                          // c2 B-h0(0)
    STAGE_BH1(0,  lds + B_OFS + REG_HALF);               // c3 B-h1(0)
    STAGE_AH1(0,  lds + A_OFS + REG_HALF);               // c4 A-h1(0)
    STAGE_AH0(BK, lds + BUF_STRIDE + A_OFS);             // c5 A-h0(1)
    STAGE_BH0(BK, lds + BUF_STRIDE + B_OFS);             // c6 B-h0(1)
    STAGE_BH1(BK, lds + BUF_STRIDE + B_OFS + REG_HALF);  // c7 B-h1(1)
    asm volatile("s_waitcnt vmcnt(6)" ::: "memory");     // c1..c4 proven
    SGB();
    BARRIER();

    bf16x8 afL[4][2], afH[4][2], bfA[2][2], bfB[2][2];
    read_af(afL, lds + A_OFS, wm, lr, lk, sx);           // afL(0)
    read_bf(bfA, lds + B_OFS, wn, lr, lk, sx);           // bfA(0)
    SGB();

#define TILE_ITER(T, CB, NB)                                                   \
    {                                                                          \
        unsigned short* cb_ = (CB);                                            \
        unsigned short* nb_ = (NB);                                            \
        const int tk1 = (((T) + 1 < NT) ? (T) + 1 : NT - 1) * BK;              \
        const int tk2 = (((T) + 2 < NT) ? (T) + 2 : NT - 1) * BK;              \
        /* P1: Q1 = afL x bfA ; reads bfB ; stage A-h1(t+1)->nb */             \
        BARRIER();                                                             \
        __builtin_amdgcn_s_setprio(1);                                         \
        mfma_quad(acc, 0, 0, afL, bfA);                                        \
        read_bf(bfB, cb_ + B_OFS + REG_HALF, wn, lr, lk, sx);                  \
        STAGE_AH1(tk1, nb_ + A_OFS + REG_HALF);                                \
        __builtin_amdgcn_s_setprio(0);                                         \
        SGB();                                                                 \
        /* P2: Q2 = afL x bfB ; reads afH ; stage A-h0(t+2)->cb ; vmcnt(4) */  \
        BARRIER();                                                             \
        __builtin_amdgcn_s_setprio(1);                                         \
        mfma_quad(acc, 0, 2, afL, bfB);                                        \
        read_af(afH, cb_ + A_OFS + REG_HALF, wm, lr, lk, sx);                  \
        STAGE_AH0(tk2, cb_ + A_OFS);                                           \
        __builtin_amdgcn_s_setprio(0);                                         \
        asm volatile("s_waitcnt vmcnt(4)" ::: "memory");                       \
        SGB();                                                                 \
        /* P3: Q3 = afH x bfA ; stage B-h1(t+2)->cb */                         \
        BARRIER();                                                             \
        __builtin_amdgcn_s_setprio(1);                                         \
        mfma_quad(acc, 4, 0, afH, bfA);                                        \
        STAGE_BH1(tk2, cb_ + B_OFS + REG_HALF);                                \
        __builtin_amdgcn_s_setprio(0);                                         \
        SGB();                                                                 \
        /* P4: Q4 = afH x bfB ; reads afL,bfA(t+1) ; stage B-h0(t+2)->cb ;     \
               vmcnt(4) */                                                     \
        BARRIER();                                                             \
        __builtin_amdgcn_s_setprio(1);                                         \
        mfma_quad(acc, 4, 2, afH, bfB);                                        \
        if ((T) + 1 < NT) {                                                    \
            read_af(afL, nb_ + A_OFS, wm, lr, lk, sx);                         \
            read_bf(bfA, nb_ + B_OFS, wn, lr, lk, sx);                         \
        }                                                                      \
        STAGE_BH0(tk2, cb_ + B_OFS);                                           \
        __builtin_amdgcn_s_setprio(0);                                         \
        asm volatile("s_waitcnt vmcnt(4)" ::: "memory");                       \
        SGB();                                                                 \
    }

    for (int tt = 0; tt < NT; tt += 2) {
        TILE_ITER(tt,     lds,              lds + BUF_STRIDE);
        TILE_ITER(tt + 1, lds + BUF_STRIDE, lds);
    }
#undef TILE_ITER
#undef STAGE_AH0
#undef STAGE_AH1
#undef STAGE_BH0
#undef STAGE_BH1

    asm volatile("s_waitcnt vmcnt(0) lgkmcnt(0)" ::: "memory"); // drain DMA
    BARRIER();

    // Epilogue: C/D layout col = lane&15, row = (lane>>4)*4 + j  [m89]
    const int r0   = bm0 + wm * 128;
    const int cC0  = bn0 + wn * 64;
    const int rsub = lk << 2;
#pragma unroll
    for (int nf = 0; nf < 4; ++nf) {
        int col = cC0 + nf * 16 + lr;
        float bv = bias[col];
#pragma unroll
        for (int mf = 0; mf < 8; ++mf) {
            int row = r0 + mf * 16 + rsub;
#pragma unroll
            for (int j = 0; j < 4; ++j)
                out[(size_t)(row + j) * N + col] = acc[mf][nf][j] + bv;
        }
    }
}

extern "C" void kernel_launch(void* const* d_in, const int* in_sizes, int n_in,
                              void* d_out, int out_size, void* d_ws, size_t ws_size,
                              hipStream_t stream) {
    const float* x = (const float*)d_in[0];   // [M][K] f32
    const float* W = (const float*)d_in[1];   // [N][K] f32
    const float* b = (const float*)d_in[2];   // [N]   f32
    float* out = (float*)d_out;               // [M][N] f32

    const int N = in_sizes[2];                // 4096
    const int K = in_sizes[1] / N;            // 4096
    const int M = in_sizes[0] / K;            // 8192

    unsigned short* xq = (unsigned short*)d_ws;            // 64 MB
    unsigned short* Wb = xq + (size_t)M * K;               // 32 MB

    const int t4x = (int)(((long long)M * K) / 4);
    const int t4w = (int)(((long long)N * K) / 4);
    prep_kernel<<<(t4x + t4w + 255) / 256, 256, 0, stream>>>(x, W, xq, Wb, t4x, t4w);

    dim3 grid((M / 256) * (N / 256));         // 512 blocks
    gemm_kernel<<<grid, 512, 0, stream>>>(xq, Wb, b, out, M, N, K);
}

// Round 12
// 266.018 us; speedup vs baseline: 1.1758x; 1.1758x over previous
//
#include <hip/hip_runtime.h>

using f32x4  = __attribute__((ext_vector_type(4))) float;
using bf16x8 = __attribute__((ext_vector_type(8))) __bf16;
using u16x4  = __attribute__((ext_vector_type(4))) unsigned short;

#define BK 64
#define REG_HALF   8192      // ushorts: 128 rows x 64 cols
#define A_OFS      0
#define B_OFS      16384
#define BUF_STRIDE 32768     // one buffer = A(32KB)+B(32KB) = 64 KB

#define BARRIER() __builtin_amdgcn_s_barrier()
#define SGB()     __builtin_amdgcn_sched_barrier(0)
// allow ALU|VALU|SALU|VMEM|VMEM_RD|VMEM_WR|DS|DS_RD|DS_WR to cross; pin MFMA
#define SGB_NOMFMA() __builtin_amdgcn_sched_barrier(0x3F7)

__device__ __forceinline__ unsigned short f32_to_bf16_bits(float f) {
    unsigned int u = __builtin_bit_cast(unsigned int, f);
    u = (u + 0x7fffu + ((u >> 16) & 1u)) >> 16;
    return (unsigned short)u;
}

__device__ __forceinline__ void gload_lds16(const void* g, void* l) {
    __builtin_amdgcn_global_load_lds(
        (const __attribute__((address_space(1))) unsigned int*)g,
        (__attribute__((address_space(3))) unsigned int*)l,
        16, 0, 0);
}

// ---------------------------------------------------------------------------
// Fused prep: fake-quant x (exact-f32 math, bf16 store) + W f32->bf16.
// t4x % 256 == 0 so no wave straddles the boundary (16-lane shfl groups OK).
// ---------------------------------------------------------------------------
__global__ void prep_kernel(const float* __restrict__ x,
                            const float* __restrict__ W,
                            unsigned short* __restrict__ xq,
                            unsigned short* __restrict__ Wb,
                            int t4x, int t4w) {
    int idx = blockIdx.x * 256 + threadIdx.x;
    if (idx < t4x) {
        f32x4 v = *(const f32x4*)(x + (size_t)idx * 4);
        float am = fmaxf(fmaxf(fabsf(v[0]), fabsf(v[1])),
                         fmaxf(fabsf(v[2]), fabsf(v[3])));
        am = fmaxf(am, __shfl_xor(am, 1));
        am = fmaxf(am, __shfl_xor(am, 2));
        am = fmaxf(am, __shfl_xor(am, 4));
        am = fmaxf(am, __shfl_xor(am, 8));
        float delta = fmaxf(am / 127.0f, 1e-5f);
        u16x4 o;
#pragma unroll
        for (int i = 0; i < 4; ++i) {
            float q = rintf(v[i] / delta);           // round-half-even
            q = fminf(fmaxf(q, -127.0f), 127.0f);
            o[i] = f32_to_bf16_bits(q * delta);
        }
        *(u16x4*)(xq + (size_t)idx * 4) = o;
    } else {
        int j = idx - t4x;
        if (j < t4w) {
            f32x4 v = *(const f32x4*)(W + (size_t)j * 4);
            u16x4 o;
#pragma unroll
            for (int i = 0; i < 4; ++i) o[i] = f32_to_bf16_bits(v[i]);
            *(u16x4*)(Wb + (size_t)j * 4) = o;
        }
    }
}

// Fragment readers (region base pointer; T2-swizzled column) ---------------
__device__ __forceinline__ void read_af(bf16x8 (&dst)[4][2],
    const unsigned short* reg, int wm, int lr, int lk, int sx) {
#pragma unroll
    for (int m = 0; m < 4; ++m)
#pragma unroll
        for (int kk = 0; kk < 2; ++kk)
            dst[m][kk] = *(const bf16x8*)(reg
                + (wm * 64 + m * 16 + lr) * 64 + ((((kk << 2) + lk) ^ sx) << 3));
}

__device__ __forceinline__ void read_bf(bf16x8 (&dst)[2][2],
    const unsigned short* reg, int wn, int lr, int lk, int sx) {
#pragma unroll
    for (int n = 0; n < 2; ++n)
#pragma unroll
        for (int kk = 0; kk < 2; ++kk)
            dst[n][kk] = *(const bf16x8*)(reg
                + (wn * 32 + n * 16 + lr) * 64 + ((((kk << 2) + lk) ^ sx) << 3));
}

__device__ __forceinline__ void mfma_quad(f32x4 (&acc)[8][4], int mo, int no,
    const bf16x8 (&af)[4][2], const bf16x8 (&bf)[2][2]) {
#pragma unroll
    for (int m = 0; m < 4; ++m)
#pragma unroll
        for (int n = 0; n < 2; ++n)
#pragma unroll
            for (int kk = 0; kk < 2; ++kk)
                acc[mo + m][no + n] = __builtin_amdgcn_mfma_f32_16x16x32_bf16(
                    af[m][kk], bf[n][kk], acc[mo + m][no + n], 0, 0, 0);
}

// ---------------------------------------------------------------------------
// 256x256 bf16 GEMM (B^T). Round-10 structure (best: 55.6% MfmaUtil) with
// ONE change: the post-MFMA fence is sched_barrier(0x3F7) instead of (0) —
// all classes except MFMA may cross, so the NEXT phase's ds_read /
// global_load_lds issue slots interleave into the current MFMA cluster
// (same barrier-delimited region; program order of memory ops vs barriers
// and vmcnt fences unchanged -> round-10 RAW/WAR/vmcnt ledger unchanged;
// MFMA pinned so "M(p) < B(p+1)" WAR proofs hold).
// Phase = { reads_p ; stage_p ; [vmcnt_p] ; SGB ; BARRIER ; setprio1
//           16xMFMA setprio0 ; SGB_NOMFMA }.
// Stage stream: P1: A-h1(t+1)->nb, P2: B-h0(t+2)->cb, P3: A-h0(t+2)->cb,
//               P4: B-h1(t+2)->cb.  Reads: P1 afL, P2 bfB, P3 {rotation
// bfNEXT=nb.B-h0 first, then afH}, P4 none.
// vmcnt: P1=10, P2=8, P4=10 (ledger induction-verified in round 10).
// Registers: single rotation pair bfA_e/bfA_o (round-9 lesson: more -> 128
// cap spill); round-11 lesson: do NOT move reads after MFMA structurally.
// ---------------------------------------------------------------------------
__global__ __launch_bounds__(512, 2) void gemm_kernel(
    const unsigned short* __restrict__ A,   // [M][K] bf16 bits (quantized x)
    const unsigned short* __restrict__ B,   // [N][K] bf16 bits (W)
    const float* __restrict__ bias,         // [N]
    float* __restrict__ out,                // [M][N] f32
    int M, int N, int K)
{
    __shared__ unsigned short lds[2 * BUF_STRIDE];   // 128 KiB

    const int tid  = threadIdx.x;
    const int lane = tid & 63;
    const int wv   = tid >> 6;
    const int wm   = wv >> 2;        // 0..1  (128 rows each)
    const int wn   = wv & 3;         // 0..3  (64 cols each)
    const int lr   = lane & 15;
    const int lk   = lane >> 4;      // 0..3
    const int sx   = lr & 7;

    const int nbn = N / 256;
    const int nwg = gridDim.x;
    const int cpx = nwg >> 3;        // bijective XCD swizzle (nwg % 8 == 0)
    const int swz = (blockIdx.x & 7) * cpx + (blockIdx.x >> 3);
    const int bm0 = (swz / nbn) * 256;
    const int bn0 = (swz % nbn) * 256;

    const unsigned short* Ag = A + (size_t)bm0 * K;
    const unsigned short* Bg = B + (size_t)bn0 * K;
    const int NT = K / BK;           // 64, even

    // Hoisted per-lane staging offsets (element units, 32-bit safe).
    const int gr0 = tid >> 3,         gr1 = (512 + tid) >> 3;
    const int c0  = ((tid & 7) ^ (gr0 & 7)) << 3;
    const int c1  = ((tid & 7) ^ (gr1 & 7)) << 3;
    const int offA0 = ((((gr0 >> 6) << 7) + (gr0 & 63))) * K + c0;
    const int offA1 = ((((gr1 >> 6) << 7) + (gr1 & 63))) * K + c1;
    const int offB0 = ((((gr0 >> 5) << 6) + (gr0 & 31))) * K + c0;
    const int offB1 = ((((gr1 >> 5) << 6) + (gr1 & 31))) * K + c1;
    const int ldsu0 = tid * 8, ldsu1 = (512 + tid) * 8;

#define STAGE_AH0(TK, DST) { gload_lds16(Ag + offA0 + (TK), (DST) + ldsu0); \
                             gload_lds16(Ag + offA1 + (TK), (DST) + ldsu1); }
#define STAGE_AH1(TK, DST) { gload_lds16(Ag + offA0 + 64*K + (TK), (DST) + ldsu0); \
                             gload_lds16(Ag + offA1 + 64*K + (TK), (DST) + ldsu1); }
#define STAGE_BH0(TK, DST) { gload_lds16(Bg + offB0 + (TK), (DST) + ldsu0); \
                             gload_lds16(Bg + offB1 + (TK), (DST) + ldsu1); }
#define STAGE_BH1(TK, DST) { gload_lds16(Bg + offB0 + 32*K + (TK), (DST) + ldsu0); \
                             gload_lds16(Bg + offB1 + 32*K + (TK), (DST) + ldsu1); }

    f32x4 acc[8][4] = {};

    // Prologue, ledger call order c1..c7 (oldest first):
    STAGE_BH0(0,  lds + B_OFS);                          // c1 B-h0(0)
    STAGE_AH0(0,  lds + A_OFS);                          // c2 A-h0(0)
    STAGE_BH1(0,  lds + B_OFS + REG_HALF);               // c3 B-h1(0)
    STAGE_AH1(0,  lds + A_OFS + REG_HALF);               // c4 A-h1(0)
    STAGE_BH0(BK, lds + BUF_STRIDE + B_OFS);             // c5 B-h0(1)
    STAGE_AH0(BK, lds + BUF_STRIDE + A_OFS);             // c6 A-h0(1)
    STAGE_BH1(BK, lds + BUF_STRIDE + B_OFS + REG_HALF);  // c7 B-h1(1)
    asm volatile("s_waitcnt vmcnt(10)" ::: "memory");    // c1,c2 proven
    SGB();
    BARRIER();

    bf16x8 bfA_e[2][2], bfA_o[2][2];
    read_bf(bfA_e, lds + B_OFS, wn, lr, lk, sx);         // rotation bfA(0)
    asm volatile("s_waitcnt lgkmcnt(0)" ::: "memory");   // delivered (once)
    SGB();
    BARRIER();

#define TILE_ITER(T, CB, NB, BFA_IN, BFA_OUT)                                  \
    {                                                                          \
        unsigned short* cb_ = (CB);                                            \
        unsigned short* nb_ = (NB);                                            \
        const int tk1 = (((T) + 1 < NT) ? (T) + 1 : NT - 1) * BK;              \
        const int tk2 = (((T) + 2 < NT) ? (T) + 2 : NT - 1) * BK;              \
        bf16x8 afL_[4][2], afH_[4][2], bfB_[2][2];                             \
        /* P1: Q1 = afL x bfA_in */                                            \
        read_af(afL_, cb_ + A_OFS, wm, lr, lk, sx);                            \
        STAGE_AH1(tk1, nb_ + A_OFS + REG_HALF);                                \
        asm volatile("s_waitcnt vmcnt(10)" ::: "memory");                      \
        SGB(); BARRIER();                                                      \
        __builtin_amdgcn_s_setprio(1);                                         \
        mfma_quad(acc, 0, 0, afL_, BFA_IN);                                    \
        __builtin_amdgcn_s_setprio(0); SGB_NOMFMA();                           \
        /* P2: Q2 = afL x bfB */                                               \
        read_bf(bfB_, cb_ + B_OFS + REG_HALF, wn, lr, lk, sx);                 \
        STAGE_BH0(tk2, cb_ + B_OFS);                                           \
        asm volatile("s_waitcnt vmcnt(8)" ::: "memory");                       \
        SGB(); BARRIER();                                                      \
        __builtin_amdgcn_s_setprio(1);                                         \
        mfma_quad(acc, 0, 2, afL_, bfB_);                                      \
        __builtin_amdgcn_s_setprio(0); SGB_NOMFMA();                           \
        /* P3: rotation read FIRST (lgkm FIFO), then afH; Q3 = afH x bfA_in */ \
        read_bf(BFA_OUT, nb_ + B_OFS, wn, lr, lk, sx);                         \
        read_af(afH_, cb_ + A_OFS + REG_HALF, wm, lr, lk, sx);                 \
        STAGE_AH0(tk2, cb_ + A_OFS);                                           \
        SGB(); BARRIER();                                                      \
        __builtin_amdgcn_s_setprio(1);                                         \
        mfma_quad(acc, 4, 0, afH_, BFA_IN);                                    \
        __builtin_amdgcn_s_setprio(0); SGB_NOMFMA();                           \
        /* P4: Q4 = afH x bfB (no reads) */                                    \
        STAGE_BH1(tk2, cb_ + B_OFS + REG_HALF);                                \
        asm volatile("s_waitcnt vmcnt(10)" ::: "memory");                      \
        SGB(); BARRIER();                                                      \
        __builtin_amdgcn_s_setprio(1);                                         \
        mfma_quad(acc, 4, 2, afH_, bfB_);                                      \
        __builtin_amdgcn_s_setprio(0); SGB_NOMFMA();                           \
    }

    for (int tt = 0; tt < NT; tt += 2) {
        TILE_ITER(tt,     lds,              lds + BUF_STRIDE, bfA_e, bfA_o);
        TILE_ITER(tt + 1, lds + BUF_STRIDE, lds,              bfA_o, bfA_e);
    }
#undef TILE_ITER
#undef STAGE_AH0
#undef STAGE_AH1
#undef STAGE_BH0
#undef STAGE_BH1

    asm volatile("s_waitcnt vmcnt(0) lgkmcnt(0)" ::: "memory"); // drain DMA
    BARRIER();

    // Epilogue: C/D layout col = lane&15, row = (lane>>4)*4 + j  [m89]
    const int r0   = bm0 + wm * 128;
    const int cC0  = bn0 + wn * 64;
    const int rsub = lk << 2;
#pragma unroll
    for (int nf = 0; nf < 4; ++nf) {
        int col = cC0 + nf * 16 + lr;
        float bv = bias[col];
#pragma unroll
        for (int mf = 0; mf < 8; ++mf) {
            int row = r0 + mf * 16 + rsub;
#pragma unroll
            for (int j = 0; j < 4; ++j)
                out[(size_t)(row + j) * N + col] = acc[mf][nf][j] + bv;
        }
    }
}

extern "C" void kernel_launch(void* const* d_in, const int* in_sizes, int n_in,
                              void* d_out, int out_size, void* d_ws, size_t ws_size,
                              hipStream_t stream) {
    const float* x = (const float*)d_in[0];   // [M][K] f32
    const float* W = (const float*)d_in[1];   // [N][K] f32
    const float* b = (const float*)d_in[2];   // [N]   f32
    float* out = (float*)d_out;               // [M][N] f32

    const int N = in_sizes[2];                // 4096
    const int K = in_sizes[1] / N;            // 4096
    const int M = in_sizes[0] / K;            // 8192

    unsigned short* xq = (unsigned short*)d_ws;            // 64 MB
    unsigned short* Wb = xq + (size_t)M * K;               // 32 MB

    const int t4x = (int)(((long long)M * K) / 4);
    const int t4w = (int)(((long long)N * K) / 4);
    prep_kernel<<<(t4x + t4w + 255) / 256, 256, 0, stream>>>(x, W, xq, Wb, t4x, t4w);

    dim3 grid((M / 256) * (N / 256));         // 512 blocks
    gemm_kernel<<<grid, 512, 0, stream>>>(xq, Wb, b, out, M, N, K);
}